// Round 1
// baseline (236.171 us; speedup 1.0000x reference)
//
#include <hip/hip_runtime.h>
#include <hip/hip_fp16.h>

#define BB 4
#define CC 3
#define HH 384
#define WW 384
#define FF 5
#define KK 25            // FF*FF
#define HW (HH*WW)
#define WP 192           // 16B pair-entries per row
#define TOT (BB*HH*WP)   // entries per table copy

#define TX 64            // tile width (pixels) — 1 px per thread
#define TY 4             // tile height

typedef float fx2 __attribute__((ext_vector_type(2)));

__device__ __forceinline__ float nt_load(const float* p) {
    return __builtin_nontemporal_load(p);
}

// pack one pixel (3 fp32 channels) -> 8B: dword0 = h(c0)|h(c1)<<16, dword1 = h(c2)
__device__ __forceinline__ uint2 pack_px(float c0, float c1, float c2) {
    __half2 h01 = __floats2half2_rn(c0, c1);
    uint2 r;
    r.x = *(const unsigned int*)&h01;
    r.y = (unsigned int)__half_as_ushort(__float2half_rn(c2));
    return r;
}

// Dual fp16 pixel-pair tables: copy A entry j = pixels (2j,2j+1);
// copy B entry j = (2j+1, 2j+2 clamped). Corner pair (x0,x0+1) = one
// aligned 16B entry: j = x0>>1, copy = x0&1.
__global__ __launch_bounds__(256) void pack_kernel(
    const float* __restrict__ inp, uint4* __restrict__ tab)
{
    int t = blockIdx.x * blockDim.x + threadIdx.x;
    if (t >= TOT) return;
    int j = t % WP;
    int y = (t / WP) % HH;
    int b = t / (WP * HH);
    int p0 = 2 * j;
    int p2 = min(2 * j + 2, WW - 1);
    const float* b0 = inp + (((size_t)b * CC + 0) * HH + y) * WW;
    const float* b1 = inp + (((size_t)b * CC + 1) * HH + y) * WW;
    const float* b2 = inp + (((size_t)b * CC + 2) * HH + y) * WW;
    fx2 a0 = *(const fx2*)(b0 + p0);     // p0 even -> 8B aligned
    fx2 a1 = *(const fx2*)(b1 + p0);
    fx2 a2 = *(const fx2*)(b2 + p0);
    float c0 = b0[p2], c1 = b1[p2], c2 = b2[p2];
    uint2 q0 = pack_px(a0.x, a1.x, a2.x);
    uint2 q1 = pack_px(a0.y, a1.y, a2.y);
    uint2 q2 = pack_px(c0, c1, c2);
    tab[t]       = make_uint4(q0.x, q0.y, q1.x, q1.y);   // copy A
    tab[TOT + t] = make_uint4(q1.x, q1.y, q2.x, q2.y);   // copy B
}

__device__ __forceinline__ void unpack_pair(uint4 r,
    float& lo0, float& lo1, float& lo2, float& hi0, float& hi1, float& hi2)
{
    float2 lo01 = __half22float2(*(const __half2*)&r.x);
    float2 hi01 = __half22float2(*(const __half2*)&r.z);
    lo0 = lo01.x; lo1 = lo01.y;
    hi0 = hi01.x; hi1 = hi01.y;
    lo2 = __half2float(*(const __half*)&r.y);
    hi2 = __half2float(*(const __half*)&r.w);
}

// 1 pixel per thread, 64x4 tile per block.
// Grid = 2304 blocks = 9216 waves (9/SIMD supply); launch_bounds(256,6)
// caps VGPR at ~85 so 6 waves/SIMD stay resident (vs 4 before).
__global__ __launch_bounds__(256, 6) void dsepconv_kernel(
    const uint4* __restrict__ tab,
    const float* __restrict__ vert,
    const float* __restrict__ horiz,
    const float* __restrict__ offx,
    const float* __restrict__ offy,
    const float* __restrict__ mask,
    float* __restrict__ out)
{
    int tx = threadIdx.x & 63;          // one wave = one 64-px row segment
    int ty = threadIdx.x >> 6;
    int x  = blockIdx.x * TX + tx;
    int y  = blockIdx.y * TY + ty;
    int b  = blockIdx.z;
    int planeoff = y * WW + x;

    float v[FF], h[FF];
#pragma unroll
    for (int f = 0; f < FF; ++f) {
        v[f] = nt_load(vert  + (b * FF + f) * HW + planeoff);
        h[f] = nt_load(horiz + (b * FF + f) * HW + planeoff);
    }

    const uint4* tb = tab + (size_t)b * (HH * WP);

    float acc0 = 0.f, acc1 = 0.f, acc2 = 0.f;
    const float fy = (float)y;

#pragma unroll
    for (int ki = 0; ki < FF; ++ki) {
        const float dy = fy + (float)(ki - 2);
        const float* ox_p = offx + (size_t)(b * KK + ki * FF) * HW + planeoff;
        const float* oy_p = offy + (size_t)(b * KK + ki * FF) * HW + planeoff;
        const float* m_p  = mask + (size_t)(b * KK + ki * FF) * HW + planeoff;

        // preload the whole ki-row of streaming operands first: 15
        // independent loads in flight before any tap math consumes them
        float oxv[FF], oyv[FF], mv[FF];
#pragma unroll
        for (int kj = 0; kj < FF; ++kj) {
            oxv[kj] = nt_load(ox_p + kj * HW);
            oyv[kj] = nt_load(oy_p + kj * HW);
            mv[kj]  = nt_load(m_p  + kj * HW);
        }

#pragma unroll
        for (int kj = 0; kj < FF; ++kj) {
            float wt = v[ki] * h[kj] * mv[kj];
            float py = oyv[kj] + dy;
            float px = oxv[kj] + (float)(x + kj - 2);
            py = fminf(fmaxf(py, 0.f), (float)(HH - 1));
            px = fminf(fmaxf(px, 0.f), (float)(WW - 1));
            float y0f = floorf(py);
            float x0f = floorf(px);
            float wy = py - y0f;
            float wx = px - x0f;
            int y0 = (int)y0f;
            int x0 = (int)x0f;
            int y1 = min(y0 + 1, HH - 1);

            int j    = x0 >> 1;
            const uint4* tbs = tb + ((x0 & 1) ? TOT : 0);
            uint4 r0 = tbs[y0 * WP + j];
            uint4 r1 = tbs[y1 * WP + j];

            float a00,a01,a02,b00,b01,b02;
            float a10,a11,a12,b10,b11,b12;
            unpack_pair(r0, a00,a01,a02, b00,b01,b02);
            unpack_pair(r1, a10,a11,a12, b10,b11,b12);

            float w00 = (1.f - wy) * (1.f - wx);
            float w01 = (1.f - wy) * wx;
            float w10 = wy * (1.f - wx);
            float w11 = wy * wx;

            acc0 += wt * (a00*w00 + b00*w01 + a10*w10 + b10*w11);
            acc1 += wt * (a01*w00 + b01*w01 + a11*w10 + b11*w11);
            acc2 += wt * (a02*w00 + b02*w01 + a12*w10 + b12*w11);
        }
    }

    out[((size_t)b * CC + 0) * HW + planeoff] = acc0;
    out[((size_t)b * CC + 1) * HW + planeoff] = acc1;
    out[((size_t)b * CC + 2) * HW + planeoff] = acc2;
}

extern "C" void kernel_launch(void* const* d_in, const int* in_sizes, int n_in,
                              void* d_out, int out_size, void* d_ws, size_t ws_size,
                              hipStream_t stream) {
    const float* inp   = (const float*)d_in[0];
    const float* vert  = (const float*)d_in[1];
    const float* horiz = (const float*)d_in[2];
    const float* offx  = (const float*)d_in[3];
    const float* offy  = (const float*)d_in[4];
    const float* mask  = (const float*)d_in[5];
    float* out = (float*)d_out;
    uint4* tab = (uint4*)d_ws;   // 2 x 4.72 MB

    {
        pack_kernel<<<(TOT + 255) / 256, 256, 0, stream>>>(inp, tab);
    }
    {
        dim3 grid(WW / TX, HH / TY, BB);   // 6 x 96 x 4
        dsepconv_kernel<<<grid, 256, 0, stream>>>(
            tab, vert, horiz, offx, offy, mask, out);
    }
}